// Round 18
// baseline (259.354 us; speedup 1.0000x reference)
//
#include <hip/hip_runtime.h>
#include <math.h>

#define N_NODES 50000
#define N_EDGES 1600000
#define C 64
#define OUTC 7

#define NB 196         // coarse buckets: dst >> 8  (49999>>8 = 195)
#define BCAP 10240     // bucket capacity (mean 8192, sigma ~90)
#define CHUNK 8192     // edges per phase-1 workgroup (196 blocks = 1/CU)

// fp32 -> bf16 (RNE), packed pair into u32 (lo = even channel, hi = odd)
__device__ __forceinline__ unsigned int pk_bf16(float a, float b) {
    unsigned int ua = __float_as_uint(a);
    ua = (ua + 0x7FFFu + ((ua >> 16) & 1u)) >> 16;
    unsigned int ub = __float_as_uint(b);
    ub = (ub + 0x7FFFu + ((ub >> 16) & 1u)) >> 16;
    return ua | (ub << 16);
}

// ---------------- CSR build, phase 1: coarse binning ----------------
// Pack edge as (dst<<16)|src (both < 65536). bucket = v >> 24 (= dst>>8).
__global__ __launch_bounds__(256) void bin_kernel(const int* __restrict__ src,
                                                  const int* __restrict__ dst,
                                                  unsigned int* __restrict__ buckets,
                                                  int* __restrict__ gcursor) {
    __shared__ unsigned int staged[CHUNK];          // 32 KB
    __shared__ int hist[NB], scanb[NB], cur[NB], baseb[NB];
    const int tid = threadIdx.x;
    const int base = blockIdx.x * CHUNK;
    int n = N_EDGES - base; if (n > CHUNK) n = CHUNK;  // multiple of 4

    for (int b = tid; b < NB; b += 256) { hist[b] = 0; cur[b] = 0; }
    __syncthreads();

    const int4* src4 = (const int4*)(src + base);
    const int4* dst4 = (const int4*)(dst + base);
    unsigned int v[32];
    int nv = n >> 2;
#pragma unroll
    for (int k = 0; k < 8; ++k) {
        int i4 = k * 256 + tid;
        if (i4 < nv) {
            int4 s4 = src4[i4];
            int4 d4 = dst4[i4];
            unsigned int d0 = (unsigned int)d4.x, d1 = (unsigned int)d4.y;
            unsigned int d2 = (unsigned int)d4.z, d3 = (unsigned int)d4.w;
            v[k * 4 + 0] = (d0 << 16) | (unsigned int)s4.x;
            v[k * 4 + 1] = (d1 << 16) | (unsigned int)s4.y;
            v[k * 4 + 2] = (d2 << 16) | (unsigned int)s4.z;
            v[k * 4 + 3] = (d3 << 16) | (unsigned int)s4.w;
            atomicAdd(&hist[d0 >> 8], 1);
            atomicAdd(&hist[d1 >> 8], 1);
            atomicAdd(&hist[d2 >> 8], 1);
            atomicAdd(&hist[d3 >> 8], 1);
        }
    }
    __syncthreads();
    if (tid == 0) {
        int run = 0;
        for (int b = 0; b < NB; ++b) { scanb[b] = run; run += hist[b]; }
    }
    __syncthreads();
#pragma unroll
    for (int k = 0; k < 8; ++k) {
        int i4 = k * 256 + tid;
        if (i4 < nv) {
#pragma unroll
            for (int q = 0; q < 4; ++q) {
                unsigned int w = v[k * 4 + q];
                int b = w >> 24;
                int p = scanb[b] + atomicAdd(&cur[b], 1);
                staged[p] = w;
            }
        }
    }
    __syncthreads();
    if (tid < NB) baseb[tid] = atomicAdd(&gcursor[tid], hist[tid]);
    __syncthreads();
    for (int i = tid; i < n; i += 256) {
        unsigned int w = staged[i];
        int b = w >> 24;
        buckets[(size_t)b * BCAP + baseb[b] + (i - scanb[b])] = w;
    }
}

// ---------------- CSR build, phase 2: per-bucket local CSR ----------------
__global__ __launch_bounds__(256) void build_csr(const unsigned int* __restrict__ buckets,
                                                 const int* __restrict__ gcursor,
                                                 unsigned int* __restrict__ csr,
                                                 int* __restrict__ off) {
    __shared__ int hist[256], part[256], offx[256], cur[256];
    __shared__ int gl[NB];
    __shared__ int s_cnt, s_base;
    const int tid = threadIdx.x;
    const int b = blockIdx.x;

    hist[tid] = 0;
    cur[tid] = 0;
    if (tid < NB) gl[tid] = gcursor[tid];
    __syncthreads();
    if (tid == 0) {
        int bs = 0;
        for (int i = 0; i < b; ++i) bs += gl[i];
        s_base = bs;
        s_cnt = gl[b];
    }
    __syncthreads();
    const int cnt = s_cnt;
    const int gbase = s_base;
    const unsigned int* bk = buckets + (size_t)b * BCAP;

    for (int i = tid; i < cnt; i += 256) {
        atomicAdd(&hist[(bk[i] >> 16) & 255], 1);
    }
    __syncthreads();
    part[tid] = hist[tid];
    __syncthreads();
    for (int d = 1; d < 256; d <<= 1) {
        int t = (tid >= d) ? part[tid - d] : 0;
        __syncthreads();
        part[tid] += t;
        __syncthreads();
    }
    offx[tid] = (tid == 0) ? 0 : part[tid - 1];
    __syncthreads();
    int node = b * 256 + tid;
    if (node < N_NODES) off[node] = gbase + offx[tid];
    if (b == NB - 1 && tid == 0) off[N_NODES] = gbase + cnt;
    for (int i = tid; i < cnt; i += 256) {
        unsigned int w = bk[i];
        int dl = (w >> 16) & 255;
        int p = offx[dl] + atomicAdd(&cur[dl], 1);
        csr[gbase + p] = w & 0xFFFFu;
    }
}

// ---------------- dense linears ----------------

// Layer 1: fp32 x in, bf16 t out. Block-level cg split (cg = blockIdx&3,
// SGPR-native) -> W GEP stays provenance-clean -> s_load (K$).
__global__ __launch_bounds__(256) void linear64_x(const float* __restrict__ x,
                                                  const float* __restrict__ W,
                                                  unsigned int* __restrict__ tb) {
    const int cg = blockIdx.x & 3;
    const int r = (blockIdx.x >> 2) * 256 + threadIdx.x;
    if (r >= N_NODES) return;
    float4 xr[16];
    const float4* xp = (const float4*)(x + (size_t)r * 64);
#pragma unroll
    for (int j = 0; j < 16; ++j) xr[j] = xp[j];
    const float* xf = (const float*)xr;

    const float* Wp = W + cg * 16 * 64;   // uniform GEP -> s_load
    unsigned int* orow = tb + (size_t)r * 32 + cg * 8;
    for (int c0 = 0; c0 < 16; c0 += 8) {
        float acc[8] = {0.f, 0.f, 0.f, 0.f, 0.f, 0.f, 0.f, 0.f};
#pragma unroll
        for (int k = 0; k < 64; ++k) {
            float xv = xf[k];
#pragma unroll
            for (int j = 0; j < 8; ++j)
                acc[j] += xv * Wp[(c0 + j) * 64 + k];  // uniform -> s_load
        }
        uint4 w;
        w.x = pk_bf16(acc[0], acc[1]);
        w.y = pk_bf16(acc[2], acc[3]);
        w.z = pk_bf16(acc[4], acc[5]);
        w.w = pk_bf16(acc[6], acc[7]);
        ((uint4*)orow)[c0 >> 3] = w;
    }
}

// Layer 2: bf16 h in (packed u32 pairs), bf16 t out. Same cg split.
__global__ __launch_bounds__(256) void linear64_h(const unsigned int* __restrict__ hb,
                                                  const float* __restrict__ W,
                                                  unsigned int* __restrict__ tb) {
    const int cg = blockIdx.x & 3;
    const int r = (blockIdx.x >> 2) * 256 + threadIdx.x;
    if (r >= N_NODES) return;
    float xf[64];
    const uint4* hp = (const uint4*)(hb + (size_t)r * 32);
#pragma unroll
    for (int j = 0; j < 8; ++j) {
        uint4 u = hp[j];
        xf[j * 8 + 0] = __uint_as_float(u.x << 16);
        xf[j * 8 + 1] = __uint_as_float(u.x & 0xFFFF0000u);
        xf[j * 8 + 2] = __uint_as_float(u.y << 16);
        xf[j * 8 + 3] = __uint_as_float(u.y & 0xFFFF0000u);
        xf[j * 8 + 4] = __uint_as_float(u.z << 16);
        xf[j * 8 + 5] = __uint_as_float(u.z & 0xFFFF0000u);
        xf[j * 8 + 6] = __uint_as_float(u.w << 16);
        xf[j * 8 + 7] = __uint_as_float(u.w & 0xFFFF0000u);
    }

    const float* Wp = W + cg * 16 * 64;
    unsigned int* orow = tb + (size_t)r * 32 + cg * 8;
    for (int c0 = 0; c0 < 16; c0 += 8) {
        float acc[8] = {0.f, 0.f, 0.f, 0.f, 0.f, 0.f, 0.f, 0.f};
#pragma unroll
        for (int k = 0; k < 64; ++k) {
            float xv = xf[k];
#pragma unroll
            for (int j = 0; j < 8; ++j)
                acc[j] += xv * Wp[(c0 + j) * 64 + k];  // uniform -> s_load
        }
        uint4 w;
        w.x = pk_bf16(acc[0], acc[1]);
        w.y = pk_bf16(acc[2], acc[3]);
        w.z = pk_bf16(acc[4], acc[5]);
        w.w = pk_bf16(acc[6], acc[7]);
        ((uint4*)orow)[c0 >> 3] = w;
    }
}

// Layer 3: bf16 h in, PACKED BF16 t3 out (8 bf16 = uint4 per row, 16 B).
// Thread-per-row, W3 K$-resident.
__global__ __launch_bounds__(128) void linear7_h(const unsigned int* __restrict__ hb,
                                                 const float* __restrict__ W,
                                                 unsigned int* __restrict__ out) {
    int r = blockIdx.x * 128 + threadIdx.x;
    if (r >= N_NODES) return;
    float xf[64];
    const uint4* hp = (const uint4*)(hb + (size_t)r * 32);
#pragma unroll
    for (int j = 0; j < 8; ++j) {
        uint4 u = hp[j];
        xf[j * 8 + 0] = __uint_as_float(u.x << 16);
        xf[j * 8 + 1] = __uint_as_float(u.x & 0xFFFF0000u);
        xf[j * 8 + 2] = __uint_as_float(u.y << 16);
        xf[j * 8 + 3] = __uint_as_float(u.y & 0xFFFF0000u);
        xf[j * 8 + 4] = __uint_as_float(u.z << 16);
        xf[j * 8 + 5] = __uint_as_float(u.z & 0xFFFF0000u);
        xf[j * 8 + 6] = __uint_as_float(u.w << 16);
        xf[j * 8 + 7] = __uint_as_float(u.w & 0xFFFF0000u);
    }

    float acc[7] = {0.f, 0.f, 0.f, 0.f, 0.f, 0.f, 0.f};
#pragma unroll
    for (int k = 0; k < 64; ++k) {
        float xv = xf[k];
#pragma unroll
        for (int j = 0; j < 7; ++j)
            acc[j] += xv * W[j * 64 + k];  // uniform -> s_load
    }
    uint4 w;
    w.x = pk_bf16(acc[0], acc[1]);
    w.y = pk_bf16(acc[2], acc[3]);
    w.z = pk_bf16(acc[4], acc[5]);
    w.w = pk_bf16(acc[6], 0.f);
    ((uint4*)(out + (size_t)r * 4))[0] = w;
}

// ---------------- gather aggregation: bf16 table -> bf16 h ----------------

// Lane map: slot = lane>>3 (8 edge slots), ch8 = lane&7 (uint4 = 8 bf16 ch).
// Regular (cached) csr loads — L1 line reuse matters (round-15 lesson).
__global__ __launch_bounds__(256) void gather64b(const int* __restrict__ off,
                                                 const unsigned int* __restrict__ csr_src,
                                                 const unsigned int* __restrict__ tb,
                                                 const float* __restrict__ b,
                                                 unsigned int* __restrict__ hb) {
    int node = blockIdx.x * 4 + (threadIdx.x >> 6);
    if (node >= N_NODES) return;
    const int lane = threadIdx.x & 63;
    const int slot = lane >> 3;
    const int ch8  = lane & 7;
    int e0 = off[node], e1 = off[node + 1];
    const uint4* t4 = (const uint4*)tb;
    float s[8] = {0.f, 0.f, 0.f, 0.f, 0.f, 0.f, 0.f, 0.f};
    for (int e = e0; e < e1; e += 16) {
        int i0 = e + slot;
        int i1 = e + 8 + slot;
        bool p0 = i0 < e1, p1 = i1 < e1;
        unsigned int a0 = csr_src[p0 ? i0 : e];
        unsigned int a1 = csr_src[p1 ? i1 : e];
        uint4 v0 = t4[(size_t)a0 * 8 + ch8];
        uint4 v1 = t4[(size_t)a1 * 8 + ch8];
        if (p0) {
            s[0] += __uint_as_float(v0.x << 16);
            s[1] += __uint_as_float(v0.x & 0xFFFF0000u);
            s[2] += __uint_as_float(v0.y << 16);
            s[3] += __uint_as_float(v0.y & 0xFFFF0000u);
            s[4] += __uint_as_float(v0.z << 16);
            s[5] += __uint_as_float(v0.z & 0xFFFF0000u);
            s[6] += __uint_as_float(v0.w << 16);
            s[7] += __uint_as_float(v0.w & 0xFFFF0000u);
        }
        if (p1) {
            s[0] += __uint_as_float(v1.x << 16);
            s[1] += __uint_as_float(v1.x & 0xFFFF0000u);
            s[2] += __uint_as_float(v1.y << 16);
            s[3] += __uint_as_float(v1.y & 0xFFFF0000u);
            s[4] += __uint_as_float(v1.z << 16);
            s[5] += __uint_as_float(v1.z & 0xFFFF0000u);
            s[6] += __uint_as_float(v1.w << 16);
            s[7] += __uint_as_float(v1.w & 0xFFFF0000u);
        }
    }
#pragma unroll
    for (int d = 8; d <= 32; d <<= 1) {
#pragma unroll
        for (int j = 0; j < 8; ++j) s[j] += __shfl_xor(s[j], d, 64);
    }
    if (lane < 8) {
        const float4 b0 = ((const float4*)b)[ch8 * 2];
        const float4 b1 = ((const float4*)b)[ch8 * 2 + 1];
        float r0 = fmaxf(s[0] + b0.x, 0.f);
        float r1 = fmaxf(s[1] + b0.y, 0.f);
        float r2 = fmaxf(s[2] + b0.z, 0.f);
        float r3 = fmaxf(s[3] + b0.w, 0.f);
        float r4 = fmaxf(s[4] + b1.x, 0.f);
        float r5 = fmaxf(s[5] + b1.y, 0.f);
        float r6 = fmaxf(s[6] + b1.z, 0.f);
        float r7 = fmaxf(s[7] + b1.w, 0.f);
        uint4 w;
        w.x = pk_bf16(r0, r1);
        w.y = pk_bf16(r2, r3);
        w.z = pk_bf16(r4, r5);
        w.w = pk_bf16(r6, r7);
        ((uint4*)(hb + (size_t)node * 32))[ch8] = w;
    }
}

// 7-ch gather + bias + log_softmax (bf16 t3, 16 B rows, 0.8 MB table).
// slot = lane>>1 (32 edge slots), h = lane&1 (uint2 = 4 bf16 channels).
__global__ __launch_bounds__(256) void gather7_lsm(const int* __restrict__ off,
                                                   const unsigned int* __restrict__ csr_src,
                                                   const unsigned int* __restrict__ t3,
                                                   const float* __restrict__ b,
                                                   float* __restrict__ out) {
    int node = blockIdx.x * 4 + (threadIdx.x >> 6);
    if (node >= N_NODES) return;
    const int lane = threadIdx.x & 63;
    const int slot = lane >> 1;
    const int h    = lane & 1;
    int e0 = off[node], e1 = off[node + 1];
    const uint2* t2 = (const uint2*)t3;
    float sx = 0.f, sy = 0.f, sz = 0.f, sw = 0.f;
    for (int e = e0 + slot; e < e1; e += 32) {
        unsigned int s = csr_src[e];
        uint2 v = t2[(size_t)s * 2 + h];
        sx += __uint_as_float(v.x << 16);
        sy += __uint_as_float(v.x & 0xFFFF0000u);
        sz += __uint_as_float(v.y << 16);
        sw += __uint_as_float(v.y & 0xFFFF0000u);
    }
#pragma unroll
    for (int d = 2; d <= 32; d <<= 1) {
        sx += __shfl_xor(sx, d, 64); sy += __shfl_xor(sy, d, 64);
        sz += __shfl_xor(sz, d, 64); sw += __shfl_xor(sw, d, 64);
    }
    float z0 = sx + b[h * 4 + 0];
    float z1 = sy + b[h * 4 + 1];
    float z2 = sz + b[h * 4 + 2];
    float z3 = (h == 0) ? (sw + b[3]) : -1e30f;
    float m = fmaxf(fmaxf(z0, z1), fmaxf(z2, z3));
    m = fmaxf(m, __shfl_xor(m, 1, 64));
    float ex = __expf(z0 - m) + __expf(z1 - m) + __expf(z2 - m) + __expf(z3 - m);
    ex += __shfl_xor(ex, 1, 64);
    float l = m + __logf(ex);
    if (lane < 2) {
        float* o = out + (size_t)node * 7 + h * 4;
        o[0] = z0 - l; o[1] = z1 - l; o[2] = z2 - l;
        if (h == 0) o[3] = z3 - l;
    }
}

extern "C" void kernel_launch(void* const* d_in, const int* in_sizes, int n_in,
                              void* d_out, int out_size, void* d_ws, size_t ws_size,
                              hipStream_t stream) {
    const float* x  = (const float*)d_in[0];
    const int*   ei = (const int*)d_in[1];
    const float* W1 = (const float*)d_in[2];
    const float* b1 = (const float*)d_in[3];
    const float* W2 = (const float*)d_in[4];
    const float* b2 = (const float*)d_in[5];
    const float* W3 = (const float*)d_in[6];
    const float* b3 = (const float*)d_in[7];
    float* out = (float*)d_out;

    const int* src = ei;
    const int* dst = ei + N_EDGES;

    // workspace: A region (12.8 MB): phase-1 buckets (8.03 MB, dead after
    // build_csr) -> bf16 t table (6.4 MB) -> bf16 t3 (0.8 MB).
    // B region holds the packed bf16 h table (6.4 MB).
    float* A = (float*)d_ws;                       // 12.8 MB
    float* B = A + (size_t)N_NODES * C;            // 12.8 MB
    unsigned int* csr = (unsigned int*)(B + (size_t)N_NODES * C);  // 6.4 MB u32
    int* off     = (int*)(csr + N_EDGES);          // 50001
    int* gcursor = off + N_NODES + 8;              // 196
    unsigned int* buckets = (unsigned int*)A;      // aliases A
    unsigned int* Abf     = (unsigned int*)A;      // bf16 t-table view
    unsigned int* Hbf     = (unsigned int*)B;      // bf16 h-table view

    const int l64grid = ((N_NODES + 255) / 256) * 4;  // 196 rowgroups x 4 cgs
    const int l7grid  = (N_NODES + 127) / 128;        // 391
    const int ngrid   = (N_NODES + 3) / 4;            // 12500

    // ---- CSR build
    (void)hipMemsetAsync(gcursor, 0, NB * sizeof(int), stream);
    bin_kernel<<<(N_EDGES + CHUNK - 1) / CHUNK, 256, 0, stream>>>(src, dst, buckets, gcursor);
    build_csr<<<NB, 256, 0, stream>>>(buckets, gcursor, csr, off);

    // ---- layer 1 (A free after build_csr)
    linear64_x<<<l64grid, 256, 0, stream>>>(x, W1, Abf);
    gather64b<<<ngrid, 256, 0, stream>>>(off, csr, Abf, b1, Hbf);

    // ---- layer 2
    linear64_h<<<l64grid, 256, 0, stream>>>(Hbf, W2, Abf);
    gather64b<<<ngrid, 256, 0, stream>>>(off, csr, Abf, b2, Hbf);

    // ---- layer 3 (bf16 t3, 16 B rows, written into A after t dead)
    linear7_h<<<l7grid, 128, 0, stream>>>(Hbf, W3, Abf);
    gather7_lsm<<<ngrid, 256, 0, stream>>>(off, csr, Abf, b3, out);
}

// Round 19
// 232.350 us; speedup vs baseline: 1.1162x; 1.1162x over previous
//
#include <hip/hip_runtime.h>
#include <math.h>

#define N_NODES 50000
#define N_EDGES 1600000
#define C 64
#define OUTC 7

#define NB 196         // coarse buckets: dst >> 8  (49999>>8 = 195)
#define BCAP 10240     // bucket capacity (mean 8192, sigma ~90)
#define CHUNK 8192     // edges per phase-1 workgroup (196 blocks = 1/CU)

typedef __attribute__((ext_vector_type(8))) short bf16x8;   // 8 bf16 = 4 VGPR
typedef __attribute__((ext_vector_type(4))) float f32x4;    // MFMA acc

// fp32 -> bf16 (RNE), packed pair into u32 (lo = even channel, hi = odd)
__device__ __forceinline__ unsigned int pk_bf16(float a, float b) {
    unsigned int ua = __float_as_uint(a);
    ua = (ua + 0x7FFFu + ((ua >> 16) & 1u)) >> 16;
    unsigned int ub = __float_as_uint(b);
    ub = (ub + 0x7FFFu + ((ub >> 16) & 1u)) >> 16;
    return ua | (ub << 16);
}

union U4B8 { uint4 u; bf16x8 s; };

// ---------------- CSR build, phase 1: coarse binning ----------------
__global__ __launch_bounds__(256) void bin_kernel(const int* __restrict__ src,
                                                  const int* __restrict__ dst,
                                                  unsigned int* __restrict__ buckets,
                                                  int* __restrict__ gcursor) {
    __shared__ unsigned int staged[CHUNK];          // 32 KB
    __shared__ int hist[NB], scanb[NB], cur[NB], baseb[NB];
    const int tid = threadIdx.x;
    const int base = blockIdx.x * CHUNK;
    int n = N_EDGES - base; if (n > CHUNK) n = CHUNK;

    for (int b = tid; b < NB; b += 256) { hist[b] = 0; cur[b] = 0; }
    __syncthreads();

    const int4* src4 = (const int4*)(src + base);
    const int4* dst4 = (const int4*)(dst + base);
    unsigned int v[32];
    int nv = n >> 2;
#pragma unroll
    for (int k = 0; k < 8; ++k) {
        int i4 = k * 256 + tid;
        if (i4 < nv) {
            int4 s4 = src4[i4];
            int4 d4 = dst4[i4];
            unsigned int d0 = (unsigned int)d4.x, d1 = (unsigned int)d4.y;
            unsigned int d2 = (unsigned int)d4.z, d3 = (unsigned int)d4.w;
            v[k * 4 + 0] = (d0 << 16) | (unsigned int)s4.x;
            v[k * 4 + 1] = (d1 << 16) | (unsigned int)s4.y;
            v[k * 4 + 2] = (d2 << 16) | (unsigned int)s4.z;
            v[k * 4 + 3] = (d3 << 16) | (unsigned int)s4.w;
            atomicAdd(&hist[d0 >> 8], 1);
            atomicAdd(&hist[d1 >> 8], 1);
            atomicAdd(&hist[d2 >> 8], 1);
            atomicAdd(&hist[d3 >> 8], 1);
        }
    }
    __syncthreads();
    if (tid == 0) {
        int run = 0;
        for (int b = 0; b < NB; ++b) { scanb[b] = run; run += hist[b]; }
    }
    __syncthreads();
#pragma unroll
    for (int k = 0; k < 8; ++k) {
        int i4 = k * 256 + tid;
        if (i4 < nv) {
#pragma unroll
            for (int q = 0; q < 4; ++q) {
                unsigned int w = v[k * 4 + q];
                int b = w >> 24;
                int p = scanb[b] + atomicAdd(&cur[b], 1);
                staged[p] = w;
            }
        }
    }
    __syncthreads();
    if (tid < NB) baseb[tid] = atomicAdd(&gcursor[tid], hist[tid]);
    __syncthreads();
    for (int i = tid; i < n; i += 256) {
        unsigned int w = staged[i];
        int b = w >> 24;
        buckets[(size_t)b * BCAP + baseb[b] + (i - scanb[b])] = w;
    }
}

// ---------------- CSR build, phase 2: per-bucket local CSR ----------------
__global__ __launch_bounds__(256) void build_csr(const unsigned int* __restrict__ buckets,
                                                 const int* __restrict__ gcursor,
                                                 unsigned int* __restrict__ csr,
                                                 int* __restrict__ off) {
    __shared__ int hist[256], part[256], offx[256], cur[256];
    __shared__ int gl[NB];
    __shared__ int s_cnt, s_base;
    const int tid = threadIdx.x;
    const int b = blockIdx.x;

    hist[tid] = 0;
    cur[tid] = 0;
    if (tid < NB) gl[tid] = gcursor[tid];
    __syncthreads();
    if (tid == 0) {
        int bs = 0;
        for (int i = 0; i < b; ++i) bs += gl[i];
        s_base = bs;
        s_cnt = gl[b];
    }
    __syncthreads();
    const int cnt = s_cnt;
    const int gbase = s_base;
    const unsigned int* bk = buckets + (size_t)b * BCAP;

    for (int i = tid; i < cnt; i += 256) {
        atomicAdd(&hist[(bk[i] >> 16) & 255], 1);
    }
    __syncthreads();
    part[tid] = hist[tid];
    __syncthreads();
    for (int d = 1; d < 256; d <<= 1) {
        int t = (tid >= d) ? part[tid - d] : 0;
        __syncthreads();
        part[tid] += t;
        __syncthreads();
    }
    offx[tid] = (tid == 0) ? 0 : part[tid - 1];
    __syncthreads();
    int node = b * 256 + tid;
    if (node < N_NODES) off[node] = gbase + offx[tid];
    if (b == NB - 1 && tid == 0) off[N_NODES] = gbase + cnt;
    for (int i = tid; i < cnt; i += 256) {
        unsigned int w = bk[i];
        int dl = (w >> 16) & 255;
        int p = offx[dl] + atomicAdd(&cur[dl], 1);
        csr[gbase + p] = w & 0xFFFFu;
    }
}

// ---------------- packing kernels ----------------

// fp32 x [50000][64] -> packed bf16 table (row = 32 u32)
__global__ __launch_bounds__(256) void pack_x(const float* __restrict__ x,
                                              unsigned int* __restrict__ xb) {
    int idx = blockIdx.x * 256 + threadIdx.x;
    if (idx >= N_NODES * 32) return;
    const float2* x2 = (const float2*)x;
    float2 v = x2[idx];
    xb[idx] = pk_bf16(v.x, v.y);
}

// fp32 W [64][64] row-major -> packed bf16 Wb (row n = 32 u32, pairs along k)
__global__ __launch_bounds__(256) void pack_w(const float* __restrict__ W,
                                              unsigned int* __restrict__ Wb) {
    int idx = blockIdx.x * 256 + threadIdx.x;
    if (idx >= 64 * 32) return;
    const float2* w2 = (const float2*)W;
    float2 v = w2[idx];
    Wb[idx] = pk_bf16(v.x, v.y);
}

// ---------------- MFMA linear: bf16 table @ Wb^T -> bf16 table ----------
// One wave = 16 rows x 64 cols. A frag: m=lane&15, k=quad*8+j (uint4 = 8 bf16).
// W stored [n][k] == B^T row-major -> B frag loads with the same pattern
// (n=lane&15, k=quad*8+j). D: col=lane&15, row=quad*4+reg (m89/m91-verified).
__global__ __launch_bounds__(256) void linear64_mfma(const unsigned int* __restrict__ in,
                                                     const unsigned int* __restrict__ Wb,
                                                     unsigned int* __restrict__ out) {
    const int wave = threadIdx.x >> 6;
    const int lane = threadIdx.x & 63;
    const int quad = lane >> 4;
    const int l16  = lane & 15;
    const int rbase = blockIdx.x * 64 + wave * 16;
    if (rbase >= N_NODES) return;   // 50000 = 3125*16, tail is wave-aligned

    // B frags: 4 col-tiles x 2 k-halves, loaded once (W row = 32 u32)
    U4B8 bfrag[4][2];
#pragma unroll
    for (int ct = 0; ct < 4; ++ct)
#pragma unroll
        for (int kt = 0; kt < 2; ++kt)
            bfrag[ct][kt].u = *(const uint4*)(Wb + (ct * 16 + l16) * 32 + kt * 16 + quad * 4);

    // A frags: 2 k-halves for this wave's 16 rows
    U4B8 afrag[2];
#pragma unroll
    for (int kt = 0; kt < 2; ++kt)
        afrag[kt].u = *(const uint4*)(in + (size_t)(rbase + l16) * 32 + kt * 16 + quad * 4);

    f32x4 acc[4];
#pragma unroll
    for (int ct = 0; ct < 4; ++ct) {
        f32x4 z = {0.f, 0.f, 0.f, 0.f};
        z = __builtin_amdgcn_mfma_f32_16x16x32_bf16(afrag[0].s, bfrag[ct][0].s, z, 0, 0, 0);
        z = __builtin_amdgcn_mfma_f32_16x16x32_bf16(afrag[1].s, bfrag[ct][1].s, z, 0, 0, 0);
        acc[ct] = z;
    }

    // D -> packed bf16: pair col c (even) with c+1 via shfl_xor(1)
    const int colp = l16 >> 1;
    const bool even = (l16 & 1) == 0;
#pragma unroll
    for (int ct = 0; ct < 4; ++ct) {
#pragma unroll
        for (int i = 0; i < 4; ++i) {
            float v = acc[ct][i];
            float p = __shfl_xor(v, 1, 64);
            if (even) {
                int row = rbase + quad * 4 + i;
                out[(size_t)row * 32 + ct * 8 + colp] = pk_bf16(v, p);
            }
        }
    }
}

// Layer 3: bf16 h in, packed bf16 t3 out (uint4 per row). W3 fp32 K$-resident.
__global__ __launch_bounds__(128) void linear7_h(const unsigned int* __restrict__ hb,
                                                 const float* __restrict__ W,
                                                 unsigned int* __restrict__ out) {
    int r = blockIdx.x * 128 + threadIdx.x;
    if (r >= N_NODES) return;
    float xf[64];
    const uint4* hp = (const uint4*)(hb + (size_t)r * 32);
#pragma unroll
    for (int j = 0; j < 8; ++j) {
        uint4 u = hp[j];
        xf[j * 8 + 0] = __uint_as_float(u.x << 16);
        xf[j * 8 + 1] = __uint_as_float(u.x & 0xFFFF0000u);
        xf[j * 8 + 2] = __uint_as_float(u.y << 16);
        xf[j * 8 + 3] = __uint_as_float(u.y & 0xFFFF0000u);
        xf[j * 8 + 4] = __uint_as_float(u.z << 16);
        xf[j * 8 + 5] = __uint_as_float(u.z & 0xFFFF0000u);
        xf[j * 8 + 6] = __uint_as_float(u.w << 16);
        xf[j * 8 + 7] = __uint_as_float(u.w & 0xFFFF0000u);
    }

    float acc[7] = {0.f, 0.f, 0.f, 0.f, 0.f, 0.f, 0.f};
#pragma unroll
    for (int k = 0; k < 64; ++k) {
        float xv = xf[k];
#pragma unroll
        for (int j = 0; j < 7; ++j)
            acc[j] += xv * W[j * 64 + k];  // uniform -> s_load
    }
    uint4 w;
    w.x = pk_bf16(acc[0], acc[1]);
    w.y = pk_bf16(acc[2], acc[3]);
    w.z = pk_bf16(acc[4], acc[5]);
    w.w = pk_bf16(acc[6], 0.f);
    ((uint4*)(out + (size_t)r * 4))[0] = w;
}

// ---------------- gather aggregation: bf16 table -> bf16 h ----------------
__global__ __launch_bounds__(256) void gather64b(const int* __restrict__ off,
                                                 const unsigned int* __restrict__ csr_src,
                                                 const unsigned int* __restrict__ tb,
                                                 const float* __restrict__ b,
                                                 unsigned int* __restrict__ hb) {
    int node = blockIdx.x * 4 + (threadIdx.x >> 6);
    if (node >= N_NODES) return;
    const int lane = threadIdx.x & 63;
    const int slot = lane >> 3;
    const int ch8  = lane & 7;
    int e0 = off[node], e1 = off[node + 1];
    const uint4* t4 = (const uint4*)tb;
    float s[8] = {0.f, 0.f, 0.f, 0.f, 0.f, 0.f, 0.f, 0.f};
    for (int e = e0; e < e1; e += 16) {
        int i0 = e + slot;
        int i1 = e + 8 + slot;
        bool p0 = i0 < e1, p1 = i1 < e1;
        unsigned int a0 = csr_src[p0 ? i0 : e];
        unsigned int a1 = csr_src[p1 ? i1 : e];
        uint4 v0 = t4[(size_t)a0 * 8 + ch8];
        uint4 v1 = t4[(size_t)a1 * 8 + ch8];
        if (p0) {
            s[0] += __uint_as_float(v0.x << 16);
            s[1] += __uint_as_float(v0.x & 0xFFFF0000u);
            s[2] += __uint_as_float(v0.y << 16);
            s[3] += __uint_as_float(v0.y & 0xFFFF0000u);
            s[4] += __uint_as_float(v0.z << 16);
            s[5] += __uint_as_float(v0.z & 0xFFFF0000u);
            s[6] += __uint_as_float(v0.w << 16);
            s[7] += __uint_as_float(v0.w & 0xFFFF0000u);
        }
        if (p1) {
            s[0] += __uint_as_float(v1.x << 16);
            s[1] += __uint_as_float(v1.x & 0xFFFF0000u);
            s[2] += __uint_as_float(v1.y << 16);
            s[3] += __uint_as_float(v1.y & 0xFFFF0000u);
            s[4] += __uint_as_float(v1.z << 16);
            s[5] += __uint_as_float(v1.z & 0xFFFF0000u);
            s[6] += __uint_as_float(v1.w << 16);
            s[7] += __uint_as_float(v1.w & 0xFFFF0000u);
        }
    }
#pragma unroll
    for (int d = 8; d <= 32; d <<= 1) {
#pragma unroll
        for (int j = 0; j < 8; ++j) s[j] += __shfl_xor(s[j], d, 64);
    }
    if (lane < 8) {
        const float4 b0 = ((const float4*)b)[ch8 * 2];
        const float4 b1 = ((const float4*)b)[ch8 * 2 + 1];
        float r0 = fmaxf(s[0] + b0.x, 0.f);
        float r1 = fmaxf(s[1] + b0.y, 0.f);
        float r2 = fmaxf(s[2] + b0.z, 0.f);
        float r3 = fmaxf(s[3] + b0.w, 0.f);
        float r4 = fmaxf(s[4] + b1.x, 0.f);
        float r5 = fmaxf(s[5] + b1.y, 0.f);
        float r6 = fmaxf(s[6] + b1.z, 0.f);
        float r7 = fmaxf(s[7] + b1.w, 0.f);
        uint4 w;
        w.x = pk_bf16(r0, r1);
        w.y = pk_bf16(r2, r3);
        w.z = pk_bf16(r4, r5);
        w.w = pk_bf16(r6, r7);
        ((uint4*)(hb + (size_t)node * 32))[ch8] = w;
    }
}

// 7-ch gather + bias + log_softmax (bf16 t3, 16 B rows).
__global__ __launch_bounds__(256) void gather7_lsm(const int* __restrict__ off,
                                                   const unsigned int* __restrict__ csr_src,
                                                   const unsigned int* __restrict__ t3,
                                                   const float* __restrict__ b,
                                                   float* __restrict__ out) {
    int node = blockIdx.x * 4 + (threadIdx.x >> 6);
    if (node >= N_NODES) return;
    const int lane = threadIdx.x & 63;
    const int slot = lane >> 1;
    const int h    = lane & 1;
    int e0 = off[node], e1 = off[node + 1];
    const uint2* t2 = (const uint2*)t3;
    float sx = 0.f, sy = 0.f, sz = 0.f, sw = 0.f;
    for (int e = e0 + slot; e < e1; e += 32) {
        unsigned int s = csr_src[e];
        uint2 v = t2[(size_t)s * 2 + h];
        sx += __uint_as_float(v.x << 16);
        sy += __uint_as_float(v.x & 0xFFFF0000u);
        sz += __uint_as_float(v.y << 16);
        sw += __uint_as_float(v.y & 0xFFFF0000u);
    }
#pragma unroll
    for (int d = 2; d <= 32; d <<= 1) {
        sx += __shfl_xor(sx, d, 64); sy += __shfl_xor(sy, d, 64);
        sz += __shfl_xor(sz, d, 64); sw += __shfl_xor(sw, d, 64);
    }
    float z0 = sx + b[h * 4 + 0];
    float z1 = sy + b[h * 4 + 1];
    float z2 = sz + b[h * 4 + 2];
    float z3 = (h == 0) ? (sw + b[3]) : -1e30f;
    float m = fmaxf(fmaxf(z0, z1), fmaxf(z2, z3));
    m = fmaxf(m, __shfl_xor(m, 1, 64));
    float ex = __expf(z0 - m) + __expf(z1 - m) + __expf(z2 - m) + __expf(z3 - m);
    ex += __shfl_xor(ex, 1, 64);
    float l = m + __logf(ex);
    if (lane < 2) {
        float* o = out + (size_t)node * 7 + h * 4;
        o[0] = z0 - l; o[1] = z1 - l; o[2] = z2 - l;
        if (h == 0) o[3] = z3 - l;
    }
}

extern "C" void kernel_launch(void* const* d_in, const int* in_sizes, int n_in,
                              void* d_out, int out_size, void* d_ws, size_t ws_size,
                              hipStream_t stream) {
    const float* x  = (const float*)d_in[0];
    const int*   ei = (const int*)d_in[1];
    const float* W1 = (const float*)d_in[2];
    const float* b1 = (const float*)d_in[3];
    const float* W2 = (const float*)d_in[4];
    const float* b2 = (const float*)d_in[5];
    const float* W3 = (const float*)d_in[6];
    const float* b3 = (const float*)d_in[7];
    float* out = (float*)d_out;

    const int* src = ei;
    const int* dst = ei + N_EDGES;

    // workspace:
    //   A (12.8 MB): buckets (8 MB, dead after build_csr) -> bf16 t table
    //                (6.4 MB) -> bf16 t3 (0.8 MB)
    //   B (12.8 MB): Hbf (first 6.4 MB) | xb (second 6.4 MB, dead after L1)
    //   then csr (6.4 MB), off, gcursor, Wb1/Wb2 (8 KB each)
    float* A = (float*)d_ws;
    float* B = A + (size_t)N_NODES * C;
    unsigned int* csr = (unsigned int*)(B + (size_t)N_NODES * C);
    int* off     = (int*)(csr + N_EDGES);          // 50001
    int* gcursor = off + N_NODES + 8;              // 196
    unsigned int* Wb1 = (unsigned int*)(gcursor + 256);   // 2048 u32
    unsigned int* Wb2 = Wb1 + 2048;                       // 2048 u32
    unsigned int* buckets = (unsigned int*)A;
    unsigned int* Abf     = (unsigned int*)A;      // bf16 t-table view
    unsigned int* Hbf     = (unsigned int*)B;      // bf16 h-table view
    unsigned int* xb      = (unsigned int*)B + (size_t)N_NODES * 32;  // bf16 x

    const int mfmagrid = (N_NODES + 63) / 64;      // 782 blocks x 4 waves
    const int l7grid   = (N_NODES + 127) / 128;    // 391
    const int ngrid    = (N_NODES + 3) / 4;        // 12500

    // ---- packing (independent of CSR build)
    pack_w<<<8, 256, 0, stream>>>(W1, Wb1);
    pack_w<<<8, 256, 0, stream>>>(W2, Wb2);
    pack_x<<<(N_NODES * 32 + 255) / 256, 256, 0, stream>>>(x, xb);

    // ---- CSR build
    (void)hipMemsetAsync(gcursor, 0, NB * sizeof(int), stream);
    bin_kernel<<<(N_EDGES + CHUNK - 1) / CHUNK, 256, 0, stream>>>(src, dst, buckets, gcursor);
    build_csr<<<NB, 256, 0, stream>>>(buckets, gcursor, csr, off);

    // ---- layer 1 (Abf aliases buckets: must follow build_csr)
    linear64_mfma<<<mfmagrid, 256, 0, stream>>>(xb, Wb1, Abf);
    gather64b<<<ngrid, 256, 0, stream>>>(off, csr, Abf, b1, Hbf);

    // ---- layer 2
    linear64_mfma<<<mfmagrid, 256, 0, stream>>>(Hbf, Wb2, Abf);
    gather64b<<<ngrid, 256, 0, stream>>>(off, csr, Abf, b2, Hbf);

    // ---- layer 3 (bf16 t3, 16 B rows)
    linear7_h<<<l7grid, 128, 0, stream>>>(Hbf, W3, Abf);
    gather7_lsm<<<ngrid, 256, 0, stream>>>(off, csr, Abf, b3, out);
}

// Round 20
// 221.321 us; speedup vs baseline: 1.1718x; 1.0498x over previous
//
#include <hip/hip_runtime.h>
#include <math.h>

#define N_NODES 50000
#define N_EDGES 1600000
#define C 64
#define OUTC 7

#define NB 196         // coarse buckets: dst >> 8  (49999>>8 = 195)
#define BCAP 10240     // bucket capacity (mean 8192, sigma ~90)
#define CHUNK 8192     // edges per phase-1 workgroup (196 blocks = 1/CU)

typedef __attribute__((ext_vector_type(8))) short bf16x8;   // 8 bf16 = 4 VGPR
typedef __attribute__((ext_vector_type(4))) float f32x4;    // MFMA acc

// fp32 -> bf16 (RNE), packed pair into u32 (lo = even channel, hi = odd)
__device__ __forceinline__ unsigned int pk_bf16(float a, float b) {
    unsigned int ua = __float_as_uint(a);
    ua = (ua + 0x7FFFu + ((ua >> 16) & 1u)) >> 16;
    unsigned int ub = __float_as_uint(b);
    ub = (ub + 0x7FFFu + ((ub >> 16) & 1u)) >> 16;
    return ua | (ub << 16);
}

union U4B8 { uint4 u; bf16x8 s; };

// ---------------- CSR build, phase 1: coarse binning ----------------
__global__ __launch_bounds__(256) void bin_kernel(const int* __restrict__ src,
                                                  const int* __restrict__ dst,
                                                  unsigned int* __restrict__ buckets,
                                                  int* __restrict__ gcursor) {
    __shared__ unsigned int staged[CHUNK];          // 32 KB
    __shared__ int hist[NB], scanb[NB], cur[NB], baseb[NB];
    const int tid = threadIdx.x;
    const int base = blockIdx.x * CHUNK;
    int n = N_EDGES - base; if (n > CHUNK) n = CHUNK;

    for (int b = tid; b < NB; b += 256) { hist[b] = 0; cur[b] = 0; }
    __syncthreads();

    const int4* src4 = (const int4*)(src + base);
    const int4* dst4 = (const int4*)(dst + base);
    unsigned int v[32];
    int nv = n >> 2;
#pragma unroll
    for (int k = 0; k < 8; ++k) {
        int i4 = k * 256 + tid;
        if (i4 < nv) {
            int4 s4 = src4[i4];
            int4 d4 = dst4[i4];
            unsigned int d0 = (unsigned int)d4.x, d1 = (unsigned int)d4.y;
            unsigned int d2 = (unsigned int)d4.z, d3 = (unsigned int)d4.w;
            v[k * 4 + 0] = (d0 << 16) | (unsigned int)s4.x;
            v[k * 4 + 1] = (d1 << 16) | (unsigned int)s4.y;
            v[k * 4 + 2] = (d2 << 16) | (unsigned int)s4.z;
            v[k * 4 + 3] = (d3 << 16) | (unsigned int)s4.w;
            atomicAdd(&hist[d0 >> 8], 1);
            atomicAdd(&hist[d1 >> 8], 1);
            atomicAdd(&hist[d2 >> 8], 1);
            atomicAdd(&hist[d3 >> 8], 1);
        }
    }
    __syncthreads();
    if (tid == 0) {
        int run = 0;
        for (int b = 0; b < NB; ++b) { scanb[b] = run; run += hist[b]; }
    }
    __syncthreads();
#pragma unroll
    for (int k = 0; k < 8; ++k) {
        int i4 = k * 256 + tid;
        if (i4 < nv) {
#pragma unroll
            for (int q = 0; q < 4; ++q) {
                unsigned int w = v[k * 4 + q];
                int b = w >> 24;
                int p = scanb[b] + atomicAdd(&cur[b], 1);
                staged[p] = w;
            }
        }
    }
    __syncthreads();
    if (tid < NB) baseb[tid] = atomicAdd(&gcursor[tid], hist[tid]);
    __syncthreads();
    for (int i = tid; i < n; i += 256) {
        unsigned int w = staged[i];
        int b = w >> 24;
        buckets[(size_t)b * BCAP + baseb[b] + (i - scanb[b])] = w;
    }
}

// ---------------- CSR build, phase 2: per-bucket local CSR ----------------
__global__ __launch_bounds__(256) void build_csr(const unsigned int* __restrict__ buckets,
                                                 const int* __restrict__ gcursor,
                                                 unsigned int* __restrict__ csr,
                                                 int* __restrict__ off) {
    __shared__ int hist[256], part[256], offx[256], cur[256];
    __shared__ int gl[NB];
    __shared__ int s_cnt, s_base;
    const int tid = threadIdx.x;
    const int b = blockIdx.x;

    hist[tid] = 0;
    cur[tid] = 0;
    if (tid < NB) gl[tid] = gcursor[tid];
    __syncthreads();
    if (tid == 0) {
        int bs = 0;
        for (int i = 0; i < b; ++i) bs += gl[i];
        s_base = bs;
        s_cnt = gl[b];
    }
    __syncthreads();
    const int cnt = s_cnt;
    const int gbase = s_base;
    const unsigned int* bk = buckets + (size_t)b * BCAP;

    for (int i = tid; i < cnt; i += 256) {
        atomicAdd(&hist[(bk[i] >> 16) & 255], 1);
    }
    __syncthreads();
    part[tid] = hist[tid];
    __syncthreads();
    for (int d = 1; d < 256; d <<= 1) {
        int t = (tid >= d) ? part[tid - d] : 0;
        __syncthreads();
        part[tid] += t;
        __syncthreads();
    }
    offx[tid] = (tid == 0) ? 0 : part[tid - 1];
    __syncthreads();
    int node = b * 256 + tid;
    if (node < N_NODES) off[node] = gbase + offx[tid];
    if (b == NB - 1 && tid == 0) off[N_NODES] = gbase + cnt;
    for (int i = tid; i < cnt; i += 256) {
        unsigned int w = bk[i];
        int dl = (w >> 16) & 255;
        int p = offx[dl] + atomicAdd(&cur[dl], 1);
        csr[gbase + p] = w & 0xFFFFu;
    }
}

// ---------------- packing ----------------

// fp32 W [64][64] row-major -> packed bf16 Wb (row n = 32 u32, pairs along k)
__global__ __launch_bounds__(256) void pack_w(const float* __restrict__ W,
                                              unsigned int* __restrict__ Wb) {
    int idx = blockIdx.x * 256 + threadIdx.x;
    if (idx >= 64 * 32) return;
    const float2* w2 = (const float2*)W;
    float2 v = w2[idx];
    Wb[idx] = pk_bf16(v.x, v.y);
}

// ---------------- MFMA linears ----------------
// One wave = 16 rows x 64 cols via 8x mfma_f32_16x16x32_bf16.
// A frag: m=lane&15, k=quad*8+j. W stored [n][k] == B^T -> same pattern.
// D: col=lane&15, row=quad*4+reg (m89/m91-verified; validated in r19).

// Layer 1: fp32 x in (A-frag packed in-register), bf16 t out.
__global__ __launch_bounds__(256) void linear64_mfma_x(const float* __restrict__ x,
                                                       const unsigned int* __restrict__ Wb,
                                                       unsigned int* __restrict__ out) {
    const int wave = threadIdx.x >> 6;
    const int lane = threadIdx.x & 63;
    const int quad = lane >> 4;
    const int l16  = lane & 15;
    const int rbase = blockIdx.x * 64 + wave * 16;
    if (rbase >= N_NODES) return;

    U4B8 bfrag[4][2];
#pragma unroll
    for (int ct = 0; ct < 4; ++ct)
#pragma unroll
        for (int kt = 0; kt < 2; ++kt)
            bfrag[ct][kt].u = *(const uint4*)(Wb + (ct * 16 + l16) * 32 + kt * 16 + quad * 4);

    // A frags from fp32: row rbase+l16, k-offset kt*32 + quad*8, 8 floats
    U4B8 afrag[2];
#pragma unroll
    for (int kt = 0; kt < 2; ++kt) {
        const float4* xp = (const float4*)(x + (size_t)(rbase + l16) * 64 + kt * 32 + quad * 8);
        float4 f0 = xp[0];
        float4 f1 = xp[1];
        afrag[kt].u.x = pk_bf16(f0.x, f0.y);
        afrag[kt].u.y = pk_bf16(f0.z, f0.w);
        afrag[kt].u.z = pk_bf16(f1.x, f1.y);
        afrag[kt].u.w = pk_bf16(f1.z, f1.w);
    }

    f32x4 acc[4];
#pragma unroll
    for (int ct = 0; ct < 4; ++ct) {
        f32x4 z = {0.f, 0.f, 0.f, 0.f};
        z = __builtin_amdgcn_mfma_f32_16x16x32_bf16(afrag[0].s, bfrag[ct][0].s, z, 0, 0, 0);
        z = __builtin_amdgcn_mfma_f32_16x16x32_bf16(afrag[1].s, bfrag[ct][1].s, z, 0, 0, 0);
        acc[ct] = z;
    }

    const int colp = l16 >> 1;
    const bool even = (l16 & 1) == 0;
#pragma unroll
    for (int ct = 0; ct < 4; ++ct) {
#pragma unroll
        for (int i = 0; i < 4; ++i) {
            float v = acc[ct][i];
            float p = __shfl_xor(v, 1, 64);
            if (even) {
                int row = rbase + quad * 4 + i;
                out[(size_t)row * 32 + ct * 8 + colp] = pk_bf16(v, p);
            }
        }
    }
}

// Layer 2: bf16 table in, bf16 t out.
__global__ __launch_bounds__(256) void linear64_mfma(const unsigned int* __restrict__ in,
                                                     const unsigned int* __restrict__ Wb,
                                                     unsigned int* __restrict__ out) {
    const int wave = threadIdx.x >> 6;
    const int lane = threadIdx.x & 63;
    const int quad = lane >> 4;
    const int l16  = lane & 15;
    const int rbase = blockIdx.x * 64 + wave * 16;
    if (rbase >= N_NODES) return;

    U4B8 bfrag[4][2];
#pragma unroll
    for (int ct = 0; ct < 4; ++ct)
#pragma unroll
        for (int kt = 0; kt < 2; ++kt)
            bfrag[ct][kt].u = *(const uint4*)(Wb + (ct * 16 + l16) * 32 + kt * 16 + quad * 4);

    U4B8 afrag[2];
#pragma unroll
    for (int kt = 0; kt < 2; ++kt)
        afrag[kt].u = *(const uint4*)(in + (size_t)(rbase + l16) * 32 + kt * 16 + quad * 4);

    f32x4 acc[4];
#pragma unroll
    for (int ct = 0; ct < 4; ++ct) {
        f32x4 z = {0.f, 0.f, 0.f, 0.f};
        z = __builtin_amdgcn_mfma_f32_16x16x32_bf16(afrag[0].s, bfrag[ct][0].s, z, 0, 0, 0);
        z = __builtin_amdgcn_mfma_f32_16x16x32_bf16(afrag[1].s, bfrag[ct][1].s, z, 0, 0, 0);
        acc[ct] = z;
    }

    const int colp = l16 >> 1;
    const bool even = (l16 & 1) == 0;
#pragma unroll
    for (int ct = 0; ct < 4; ++ct) {
#pragma unroll
        for (int i = 0; i < 4; ++i) {
            float v = acc[ct][i];
            float p = __shfl_xor(v, 1, 64);
            if (even) {
                int row = rbase + quad * 4 + i;
                out[(size_t)row * 32 + ct * 8 + colp] = pk_bf16(v, p);
            }
        }
    }
}

// Layer 3: bf16 h in, packed bf16 t3 out (uint4 per row). W3 fp32 K$-resident.
__global__ __launch_bounds__(128) void linear7_h(const unsigned int* __restrict__ hb,
                                                 const float* __restrict__ W,
                                                 unsigned int* __restrict__ out) {
    int r = blockIdx.x * 128 + threadIdx.x;
    if (r >= N_NODES) return;
    float xf[64];
    const uint4* hp = (const uint4*)(hb + (size_t)r * 32);
#pragma unroll
    for (int j = 0; j < 8; ++j) {
        uint4 u = hp[j];
        xf[j * 8 + 0] = __uint_as_float(u.x << 16);
        xf[j * 8 + 1] = __uint_as_float(u.x & 0xFFFF0000u);
        xf[j * 8 + 2] = __uint_as_float(u.y << 16);
        xf[j * 8 + 3] = __uint_as_float(u.y & 0xFFFF0000u);
        xf[j * 8 + 4] = __uint_as_float(u.z << 16);
        xf[j * 8 + 5] = __uint_as_float(u.z & 0xFFFF0000u);
        xf[j * 8 + 6] = __uint_as_float(u.w << 16);
        xf[j * 8 + 7] = __uint_as_float(u.w & 0xFFFF0000u);
    }

    float acc[7] = {0.f, 0.f, 0.f, 0.f, 0.f, 0.f, 0.f};
#pragma unroll
    for (int k = 0; k < 64; ++k) {
        float xv = xf[k];
#pragma unroll
        for (int j = 0; j < 7; ++j)
            acc[j] += xv * W[j * 64 + k];  // uniform -> s_load
    }
    uint4 w;
    w.x = pk_bf16(acc[0], acc[1]);
    w.y = pk_bf16(acc[2], acc[3]);
    w.z = pk_bf16(acc[4], acc[5]);
    w.w = pk_bf16(acc[6], 0.f);
    ((uint4*)(out + (size_t)r * 4))[0] = w;
}

// ---------------- gather aggregation: bf16 table -> bf16 h ----------------
// 4 independent row-loads in flight per iteration (32 edges) — typical node
// (deg ~32) completes in one iteration with MLP 4 instead of 2x2 serialized.
__global__ __launch_bounds__(256) void gather64b(const int* __restrict__ off,
                                                 const unsigned int* __restrict__ csr_src,
                                                 const unsigned int* __restrict__ tb,
                                                 const float* __restrict__ b,
                                                 unsigned int* __restrict__ hb) {
    int node = blockIdx.x * 4 + (threadIdx.x >> 6);
    if (node >= N_NODES) return;
    const int lane = threadIdx.x & 63;
    const int slot = lane >> 3;
    const int ch8  = lane & 7;
    int e0 = off[node], e1 = off[node + 1];
    const uint4* t4 = (const uint4*)tb;
    float s[8] = {0.f, 0.f, 0.f, 0.f, 0.f, 0.f, 0.f, 0.f};
    for (int e = e0; e < e1; e += 32) {
        int i0 = e + slot;
        int i1 = e + 8 + slot;
        int i2 = e + 16 + slot;
        int i3 = e + 24 + slot;
        bool p0 = i0 < e1, p1 = i1 < e1, p2 = i2 < e1, p3 = i3 < e1;
        unsigned int a0 = csr_src[p0 ? i0 : e];
        unsigned int a1 = csr_src[p1 ? i1 : e];
        unsigned int a2 = csr_src[p2 ? i2 : e];
        unsigned int a3 = csr_src[p3 ? i3 : e];
        uint4 v0 = t4[(size_t)a0 * 8 + ch8];
        uint4 v1 = t4[(size_t)a1 * 8 + ch8];
        uint4 v2 = t4[(size_t)a2 * 8 + ch8];
        uint4 v3 = t4[(size_t)a3 * 8 + ch8];
        if (p0) {
            s[0] += __uint_as_float(v0.x << 16);
            s[1] += __uint_as_float(v0.x & 0xFFFF0000u);
            s[2] += __uint_as_float(v0.y << 16);
            s[3] += __uint_as_float(v0.y & 0xFFFF0000u);
            s[4] += __uint_as_float(v0.z << 16);
            s[5] += __uint_as_float(v0.z & 0xFFFF0000u);
            s[6] += __uint_as_float(v0.w << 16);
            s[7] += __uint_as_float(v0.w & 0xFFFF0000u);
        }
        if (p1) {
            s[0] += __uint_as_float(v1.x << 16);
            s[1] += __uint_as_float(v1.x & 0xFFFF0000u);
            s[2] += __uint_as_float(v1.y << 16);
            s[3] += __uint_as_float(v1.y & 0xFFFF0000u);
            s[4] += __uint_as_float(v1.z << 16);
            s[5] += __uint_as_float(v1.z & 0xFFFF0000u);
            s[6] += __uint_as_float(v1.w << 16);
            s[7] += __uint_as_float(v1.w & 0xFFFF0000u);
        }
        if (p2) {
            s[0] += __uint_as_float(v2.x << 16);
            s[1] += __uint_as_float(v2.x & 0xFFFF0000u);
            s[2] += __uint_as_float(v2.y << 16);
            s[3] += __uint_as_float(v2.y & 0xFFFF0000u);
            s[4] += __uint_as_float(v2.z << 16);
            s[5] += __uint_as_float(v2.z & 0xFFFF0000u);
            s[6] += __uint_as_float(v2.w << 16);
            s[7] += __uint_as_float(v2.w & 0xFFFF0000u);
        }
        if (p3) {
            s[0] += __uint_as_float(v3.x << 16);
            s[1] += __uint_as_float(v3.x & 0xFFFF0000u);
            s[2] += __uint_as_float(v3.y << 16);
            s[3] += __uint_as_float(v3.y & 0xFFFF0000u);
            s[4] += __uint_as_float(v3.z << 16);
            s[5] += __uint_as_float(v3.z & 0xFFFF0000u);
            s[6] += __uint_as_float(v3.w << 16);
            s[7] += __uint_as_float(v3.w & 0xFFFF0000u);
        }
    }
#pragma unroll
    for (int d = 8; d <= 32; d <<= 1) {
#pragma unroll
        for (int j = 0; j < 8; ++j) s[j] += __shfl_xor(s[j], d, 64);
    }
    if (lane < 8) {
        const float4 b0 = ((const float4*)b)[ch8 * 2];
        const float4 b1 = ((const float4*)b)[ch8 * 2 + 1];
        float r0 = fmaxf(s[0] + b0.x, 0.f);
        float r1 = fmaxf(s[1] + b0.y, 0.f);
        float r2 = fmaxf(s[2] + b0.z, 0.f);
        float r3 = fmaxf(s[3] + b0.w, 0.f);
        float r4 = fmaxf(s[4] + b1.x, 0.f);
        float r5 = fmaxf(s[5] + b1.y, 0.f);
        float r6 = fmaxf(s[6] + b1.z, 0.f);
        float r7 = fmaxf(s[7] + b1.w, 0.f);
        uint4 w;
        w.x = pk_bf16(r0, r1);
        w.y = pk_bf16(r2, r3);
        w.z = pk_bf16(r4, r5);
        w.w = pk_bf16(r6, r7);
        ((uint4*)(hb + (size_t)node * 32))[ch8] = w;
    }
}

// 7-ch gather + bias + log_softmax (bf16 t3, 16 B rows).
__global__ __launch_bounds__(256) void gather7_lsm(const int* __restrict__ off,
                                                   const unsigned int* __restrict__ csr_src,
                                                   const unsigned int* __restrict__ t3,
                                                   const float* __restrict__ b,
                                                   float* __restrict__ out) {
    int node = blockIdx.x * 4 + (threadIdx.x >> 6);
    if (node >= N_NODES) return;
    const int lane = threadIdx.x & 63;
    const int slot = lane >> 1;
    const int h    = lane & 1;
    int e0 = off[node], e1 = off[node + 1];
    const uint2* t2 = (const uint2*)t3;
    float sx = 0.f, sy = 0.f, sz = 0.f, sw = 0.f;
    for (int e = e0 + slot; e < e1; e += 32) {
        unsigned int s = csr_src[e];
        uint2 v = t2[(size_t)s * 2 + h];
        sx += __uint_as_float(v.x << 16);
        sy += __uint_as_float(v.x & 0xFFFF0000u);
        sz += __uint_as_float(v.y << 16);
        sw += __uint_as_float(v.y & 0xFFFF0000u);
    }
#pragma unroll
    for (int d = 2; d <= 32; d <<= 1) {
        sx += __shfl_xor(sx, d, 64); sy += __shfl_xor(sy, d, 64);
        sz += __shfl_xor(sz, d, 64); sw += __shfl_xor(sw, d, 64);
    }
    float z0 = sx + b[h * 4 + 0];
    float z1 = sy + b[h * 4 + 1];
    float z2 = sz + b[h * 4 + 2];
    float z3 = (h == 0) ? (sw + b[3]) : -1e30f;
    float m = fmaxf(fmaxf(z0, z1), fmaxf(z2, z3));
    m = fmaxf(m, __shfl_xor(m, 1, 64));
    float ex = __expf(z0 - m) + __expf(z1 - m) + __expf(z2 - m) + __expf(z3 - m);
    ex += __shfl_xor(ex, 1, 64);
    float l = m + __logf(ex);
    if (lane < 2) {
        float* o = out + (size_t)node * 7 + h * 4;
        o[0] = z0 - l; o[1] = z1 - l; o[2] = z2 - l;
        if (h == 0) o[3] = z3 - l;
    }
}

extern "C" void kernel_launch(void* const* d_in, const int* in_sizes, int n_in,
                              void* d_out, int out_size, void* d_ws, size_t ws_size,
                              hipStream_t stream) {
    const float* x  = (const float*)d_in[0];
    const int*   ei = (const int*)d_in[1];
    const float* W1 = (const float*)d_in[2];
    const float* b1 = (const float*)d_in[3];
    const float* W2 = (const float*)d_in[4];
    const float* b2 = (const float*)d_in[5];
    const float* W3 = (const float*)d_in[6];
    const float* b3 = (const float*)d_in[7];
    float* out = (float*)d_out;

    const int* src = ei;
    const int* dst = ei + N_EDGES;

    // workspace:
    //   A (12.8 MB): buckets (8 MB, dead after build_csr) -> bf16 t table
    //                (6.4 MB) -> bf16 t3 (0.8 MB)
    //   B (12.8 MB): Hbf (first 6.4 MB)
    //   then csr (6.4 MB), off, gcursor, Wb1/Wb2 (8 KB each)
    float* A = (float*)d_ws;
    float* B = A + (size_t)N_NODES * C;
    unsigned int* csr = (unsigned int*)(B + (size_t)N_NODES * C);
    int* off     = (int*)(csr + N_EDGES);          // 50001
    int* gcursor = off + N_NODES + 8;              // 196
    unsigned int* Wb1 = (unsigned int*)(gcursor + 256);   // 2048 u32
    unsigned int* Wb2 = Wb1 + 2048;                       // 2048 u32
    unsigned int* buckets = (unsigned int*)A;
    unsigned int* Abf     = (unsigned int*)A;      // bf16 t-table view
    unsigned int* Hbf     = (unsigned int*)B;      // bf16 h-table view

    const int mfmagrid = (N_NODES + 63) / 64;      // 782 blocks x 4 waves
    const int l7grid   = (N_NODES + 127) / 128;    // 391
    const int ngrid    = (N_NODES + 3) / 4;        // 12500

    // ---- weight packing (independent of CSR build)
    pack_w<<<8, 256, 0, stream>>>(W1, Wb1);
    pack_w<<<8, 256, 0, stream>>>(W2, Wb2);

    // ---- CSR build
    (void)hipMemsetAsync(gcursor, 0, NB * sizeof(int), stream);
    bin_kernel<<<(N_EDGES + CHUNK - 1) / CHUNK, 256, 0, stream>>>(src, dst, buckets, gcursor);
    build_csr<<<NB, 256, 0, stream>>>(buckets, gcursor, csr, off);

    // ---- layer 1 (Abf aliases buckets: must follow build_csr)
    linear64_mfma_x<<<mfmagrid, 256, 0, stream>>>(x, Wb1, Abf);
    gather64b<<<ngrid, 256, 0, stream>>>(off, csr, Abf, b1, Hbf);

    // ---- layer 2
    linear64_mfma<<<mfmagrid, 256, 0, stream>>>(Hbf, Wb2, Abf);
    gather64b<<<ngrid, 256, 0, stream>>>(off, csr, Abf, b2, Hbf);

    // ---- layer 3 (bf16 t3, 16 B rows)
    linear7_h<<<l7grid, 128, 0, stream>>>(Hbf, W3, Abf);
    gather7_lsm<<<ngrid, 256, 0, stream>>>(off, csr, Abf, b3, out);
}